// Round 4
// baseline (1001.302 us; speedup 1.0000x reference)
//
#include <hip/hip_runtime.h>
#include <hip/hip_bf16.h>

typedef unsigned int   u32;
typedef unsigned short u16;

#define T_     24
#define LAMDA_ 0.2f

// output layout (flat f32): outs[24,64,256] | cs[64,256] | las[24,64,32] | gas[24,64,256]
#define OFF_CS  393216
#define OFF_LAS 409600
#define OFF_GAS 458752

__device__ __forceinline__ float clamp15(float x){ return fminf(15.f, fmaxf(-15.f, x)); }
__device__ __forceinline__ float rcp_(float x){ return __builtin_amdgcn_rcpf(x); }

// ---------------------------------------------------------------------------
// One block per batch element (64 blocks x 1024 threads). FP32 in, FP32 out.
//   init:  hf_g (24x256 outputs of a 768-MAC conv, Wcg staged via LDS in 3
//          chunks of 8 channels) -> Eg = exp(2*hf_g); hf_l -> El = exp(2*hf_l)
//   loop:  tanh(A+y) = 1 - 2/(E*F+1), F_d = exp(2*y_d); 24 steps with
//          block-wide barriers between phases. No workspace.
// ---------------------------------------------------------------------------
__global__ __launch_bounds__(1024) void spat_kernel(
    const float* __restrict__ li,  const float* __restrict__ gi,
    const float* __restrict__ ls,  const float* __restrict__ gs,
    const float* __restrict__ dist,
    const float* __restrict__ la0, const float* __restrict__ ga0,
    const float* __restrict__ Wcl, const float* __restrict__ bcl,
    const float* __restrict__ Wll, const float* __restrict__ bll, const float* __restrict__ vl,
    const float* __restrict__ Wcg, const float* __restrict__ bcg,
    const float* __restrict__ Wlg, const float* __restrict__ blg, const float* __restrict__ vg,
    const float* __restrict__ Wih, const float* __restrict__ bih, const float* __restrict__ bhh,
    float* __restrict__ out)
{
    __shared__ float Eg[6144];               // exp(2*hf_g[o][s]), o<24, s<256
    __shared__ float El[768];                // exp(2*hf_l[o][l]), idx o*32+l
    __shared__ __align__(16) union {
        float wcg[6144];                     // Wcg staging: 8-channel chunk (24*8*32 f32)
        struct {
            float sgred[1024];
            float red[768];
            float gbuf[768];
            float xv[288];
            float cq[256];
        } p;
    } U;
    __shared__ float ga[256], dstf[256], la[32], slbuf[32];
    __shared__ float Fl[24], Fg[24], vlf[24], vgf[24];
    __shared__ float wred[8], cbuf[2];

    const int b = blockIdx.x, tid = threadIdx.x;
    const int s = tid & 255, ogrp = tid >> 8;

    // ---- small init (first use is after later barriers) ----
    if (tid < 32)  la[tid]  = la0[b*32 + tid];
    if (tid < 256) { ga[tid] = ga0[b*256 + tid]; dstf[tid] = dist[b*256 + tid]; }
    if (tid < 24)  { vlf[tid] = vl[tid]; vgf[tid] = vg[tid]; }
    if (tid == 0)  { float s1 = 0.f; for (int d = 0; d < 24; d++) s1 += vl[d]; cbuf[0] = s1; }
    if (tid == 1)  { float s1 = 0.f; for (int d = 0; d < 24; d++) s1 += vg[d]; cbuf[1] = s1; }

    // ---- hf_g: thread (s, ogrp) accumulates 6 o's over c<24, j<32 ----
    float acc[6];
#pragma unroll
    for (int i = 0; i < 6; i++) acc[i] = bcg[ogrp*6 + i];

    for (int hc = 0; hc < 3; hc++) {
        // stage Wcg channels [hc*8, hc*8+8): LDS idx = o*256 + cc*32 + j
        for (int k = tid; k < 6144; k += 1024) {
            const int o = k >> 8, r = k & 255;       // r = cc*32 + j
            U.wcg[k] = Wcg[o*768 + hc*256 + r];
        }
        __syncthreads();
        for (int cc = 0; cc < 8; cc++) {
            const int c = hc*8 + cc;
            const float4* gp = (const float4*)(gs + ((size_t)b*196608 + c*8192 + s*32));
            float gv[32];
#pragma unroll
            for (int m = 0; m < 8; m++) {
                const float4 g = gp[m];
                gv[4*m] = g.x; gv[4*m+1] = g.y; gv[4*m+2] = g.z; gv[4*m+3] = g.w;
            }
#pragma unroll
            for (int i = 0; i < 6; i++) {
                const float4* wp = (const float4*)(U.wcg + ((ogrp*6 + i)*256 + cc*32));
                float a = acc[i];
#pragma unroll
                for (int m = 0; m < 8; m++) {
                    const float4 w = wp[m];
                    a = fmaf(w.x, gv[4*m],   a);
                    a = fmaf(w.y, gv[4*m+1], a);
                    a = fmaf(w.z, gv[4*m+2], a);
                    a = fmaf(w.w, gv[4*m+3], a);
                }
                acc[i] = a;
            }
        }
        __syncthreads();
    }
#pragma unroll
    for (int i = 0; i < 6; i++) Eg[(ogrp*6 + i)*256 + s] = __expf(2.f*clamp15(acc[i]));

    // ---- hf_l -> El ----
    if (tid < 768) {                          // o = tid>>5, l = tid&31
        const int o = tid >> 5, l = tid & 31;
        float a = bcl[o];
        for (int c = 0; c < 24; c++)
            a = fmaf(Wcl[o*24 + c], ls[b*768 + c*32 + l], a);
        El[tid] = __expf(2.f*clamp15(a));
    }
    __syncthreads();

    for (int t = 0; t < T_; t++) {
        // ---- P1: x = concat(la*l_inp, ga*g_inp) ----
        if (tid < 288) {
            float v;
            if (tid < 32) v = la[tid] * li[t*2048 + b*32 + tid];
            else { const int ss = tid - 32; v = ga[ss] * gi[t*16384 + b*256 + ss]; }
            U.p.xv[tid] = v;
        }
        __syncthreads();

        // ---- P2: gates (f-gate rows skipped; i:0-255, g:512-767, o:768-1023) ----
        if (tid < 768) {
            const int row = tid + ((tid >= 256) ? 256 : 0);
            float a = bih[row] + bhh[row];
            const float4* wp = (const float4*)(Wih + row*288);
            const float4* xp = (const float4*)U.p.xv;
#pragma unroll 8
            for (int kb = 0; kb < 72; kb++) {
                const float4 w = wp[kb], x = xp[kb];
                a = fmaf(w.x, x.x, a); a = fmaf(w.y, x.y, a);
                a = fmaf(w.z, x.z, a); a = fmaf(w.w, x.w, a);
            }
            U.p.gbuf[tid] = a;
        }
        __syncthreads();

        // ---- P3: c = sig(i)*tanh(g); h = sig(o)*tanh(c) ----
        if (tid < 256) {
            const float ig = U.p.gbuf[tid], gg = U.p.gbuf[256 + tid], ot = U.p.gbuf[512 + tid];
            const float sig_i = rcp_(1.f + __expf(-ig));
            const float th_g  = 1.f - 2.f*rcp_(1.f + __expf(2.f*clamp15(gg)));
            const float c     = sig_i * th_g;
            const float sig_o = rcp_(1.f + __expf(-ot));
            const float th_c  = 1.f - 2.f*rcp_(1.f + __expf(2.f*c));
            const float h     = sig_o * th_c;
            U.p.cq[tid] = c;
            out[t*16384 + b*256 + tid] = h;
            if (t == T_ - 1) out[OFF_CS + b*256 + tid] = c;
        }
        __syncthreads();

        // ---- P4: 48 dots (y_l 24 + y_g 24), one thread each, F = exp(2y) ----
        if (tid < 48) {
            const float* Wr = (tid < 24) ? (Wll + tid*256) : (Wlg + (tid - 24)*256);
            const float4* wp = (const float4*)Wr;
            const float4* cp = (const float4*)U.p.cq;
            float a = (tid < 24) ? bll[tid] : blg[tid - 24];
#pragma unroll 8
            for (int kb = 0; kb < 64; kb++) {
                const float4 w = wp[kb], c4 = cp[kb];
                a = fmaf(w.x, c4.x, a); a = fmaf(w.y, c4.y, a);
                a = fmaf(w.z, c4.z, a); a = fmaf(w.w, c4.w, a);
            }
            const float F = __expf(2.f*clamp15(a));
            if (tid < 24) Fl[tid] = F; else Fg[tid - 24] = F;
        }
        __syncthreads();

        // ---- P5: s_l partials: thread (l = tid/24, o = tid%24) ----
        if (tid < 768) {
            const int l = tid / 24, o = tid - l*24;
            const float E = El[o*32 + l];
            float a = 0.f;
#pragma unroll
            for (int d = 0; d < 24; d++)
                a = fmaf(vlf[d], rcp_(fmaf(E, Fl[d], 1.f)), a);
            U.p.red[tid] = a;
        }
        __syncthreads();

        // ---- P5b-a: reduce over o -> score ----
        if (tid < 32) {
            float tot = 0.f;
#pragma unroll
            for (int o2 = 0; o2 < 24; o2++) tot += U.p.red[tid*24 + o2];
            slbuf[tid] = 24.f*cbuf[0] - 2.f*tot;
        }
        __syncthreads();

        // ---- P5b-b: softmax over 32 (serial LDS) ----
        if (tid < 32) {
            float M = -3.4e38f;
#pragma unroll
            for (int k = 0; k < 32; k++) M = fmaxf(M, slbuf[k]);
            float S = 0.f;
#pragma unroll
            for (int k = 0; k < 32; k++) S += __expf(slbuf[k] - M);
            const float r = __expf(slbuf[tid] - M) * rcp_(S);
            la[tid] = r;
            out[OFF_LAS + t*2048 + b*32 + tid] = r;
        }

        // ---- P7: s_g partials: thread (s, ogrp), 6 o's x 24 d's ----
        {
            float a = 0.f;
#pragma unroll
            for (int i = 0; i < 6; i++) {
                const float E = Eg[(ogrp*6 + i)*256 + s];
#pragma unroll
                for (int d = 0; d < 24; d++)
                    a = fmaf(vgf[d], rcp_(fmaf(E, Fg[d], 1.f)), a);
            }
            U.p.sgred[tid] = a;
        }
        __syncthreads();

        // ---- P8: combine + lambda-mix + softmax over 256 (full-wave shuffles) ----
        float vv = 0.f, ee = 0.f;
        if (tid < 256) {
            const float tot = U.p.sgred[tid] + U.p.sgred[256 + tid]
                            + U.p.sgred[512 + tid] + U.p.sgred[768 + tid];
            const float sgw = 24.f*cbuf[1] - 2.f*tot;
            vv = (1.f - LAMDA_)*sgw + LAMDA_*dstf[tid];
            float m = vv;
#pragma unroll
            for (int mk = 32; mk >= 1; mk >>= 1) m = fmaxf(m, __shfl_xor(m, mk));
            if ((tid & 63) == 0) wred[tid >> 6] = m;
        }
        __syncthreads();
        if (tid < 256) {
            const float M = fmaxf(fmaxf(wred[0], wred[1]), fmaxf(wred[2], wred[3]));
            ee = __expf(vv - M);
            float ssum = ee;
#pragma unroll
            for (int mk = 32; mk >= 1; mk >>= 1) ssum += __shfl_xor(ssum, mk);
            if ((tid & 63) == 0) wred[4 + (tid >> 6)] = ssum;
        }
        __syncthreads();
        if (tid < 256) {
            const float S = wred[4] + wred[5] + wred[6] + wred[7];
            const float r = ee * rcp_(S);
            ga[tid] = r;
            out[OFF_GAS + t*16384 + b*256 + tid] = r;
        }
        __syncthreads();
    }
}

extern "C" void kernel_launch(void* const* d_in, const int* in_sizes, int n_in,
                              void* d_out, int out_size, void* d_ws, size_t ws_size,
                              hipStream_t stream)
{
    const float* li   = (const float*)d_in[0];
    const float* gi   = (const float*)d_in[1];
    const float* ls   = (const float*)d_in[2];
    const float* gs   = (const float*)d_in[3];
    const float* dist = (const float*)d_in[4];
    const float* la0  = (const float*)d_in[5];
    const float* ga0  = (const float*)d_in[6];
    const float* Wcl  = (const float*)d_in[7];
    const float* bcl  = (const float*)d_in[8];
    const float* Wll  = (const float*)d_in[9];
    const float* bll  = (const float*)d_in[10];
    const float* vl   = (const float*)d_in[11];
    const float* Wcg  = (const float*)d_in[12];
    const float* bcg  = (const float*)d_in[13];
    const float* Wlg  = (const float*)d_in[14];
    const float* blg  = (const float*)d_in[15];
    const float* vg   = (const float*)d_in[16];
    const float* Wih  = (const float*)d_in[17];
    const float* bih  = (const float*)d_in[18];
    const float* bhh  = (const float*)d_in[19];

    spat_kernel<<<64, 1024, 0, stream>>>(li, gi, ls, gs, dist, la0, ga0,
                                         Wcl, bcl, Wll, bll, vl,
                                         Wcg, bcg, Wlg, blg, vg,
                                         Wih, bih, bhh, (float*)d_out);
}